// Round 9
// baseline (189.899 us; speedup 1.0000x reference)
//
#include <hip/hip_runtime.h>

// QRNN fused kernel for MI355X.
// B=64, S=2048, VOCAB=128, HIDDEN=256, gates=768, emb=124, num=7.
//
//  - precompute_kernel (one grid, three roles):
//      blocks 0..255  : GEMM, one channel j per block, 256 thr = 128 e x 2 k-halves.
//                       emb^T staged in LDS (pad 129); Wc rows block-uniform -> s_load.
//                       Writes fp16-packed exp2-domain table G2h[e][j]={z',f'} (1KB
//                       rows: halves gather bytes vs f32, table 128KB -> better L1
//                       capture) and f32 Go[e][j]=o'.
//      block  256     : rank-4 numeric weights Wg4/Wgo4 + zero the per-batch atomic
//                       counters cnt[64] (fresh every launch -> graph-replay safe).
//      blocks 257..384: rank-4 records Xp[b*S+t] = {eo=e<<10 bits, y0..y2}{y3,pad}.
//  - scan_kernel: affine recurrence h = f*h + (1-f)*z, chunked scan (32 x 64 steps),
//      256 thr, 1 channel/thread, full 64-step unroll (r8 structure, best measured).
//      Per step: s_load record, dword gather (fp16x2) + 2 cvt, 4 pk_fma,
//      2 exp2 + shared rcp, scan update. COMBINE IS FUSED: after writing (A,Bv),
//      blocks ticket via device-scope atomicAdd(cnt[b]); the last of the 32 chunk
//      blocks folds the 32 affines, applies o-gate + W_out dot, writes out[b].
//      Removes the 3rd kernel + one graph boundary.

typedef float   f32x2 __attribute__((ext_vector_type(2)));
typedef float   f32x4 __attribute__((ext_vector_type(4)));
typedef _Float16 f16x2 __attribute__((ext_vector_type(2)));

#define NB 64
#define NS 2048
#define NH 256
#define CHUNKS 32
#define STEPS (NS / CHUNKS)   // 64
#define LOG2E 1.4426950408889634f
#define PAD 129

__global__ __launch_bounds__(256) void precompute_kernel(
    const float* __restrict__ X,     // [B][S][8]
    const float* __restrict__ emb,   // [128][124]
    const float* __restrict__ Wn,    // [4][7]
    const float* __restrict__ bn,    // [4]
    const float* __restrict__ Wc,    // [768][128]
    const float* __restrict__ bc,    // [768]
    f16x2* __restrict__ G2h,         // out [128e][256j]  (z', f') fp16, exp2-domain
    float* __restrict__ Go,          // out [128e][256j]  o' (f32)
    f32x2* __restrict__ Wg4,         // out [4][256]
    float* __restrict__ Wgo4,        // out [4][256]
    float* __restrict__ Xp,          // out [B*S][8] packed rank-4 records
    int*   __restrict__ cnt)         // out [64] zeroed ticket counters
{
    const int tid = threadIdx.x;
    const int blk = blockIdx.x;

    if (blk < 256) {
        __shared__ float M[124 * PAD];      // emb^T: M[k*PAD + e] = emb[e][k]
        __shared__ float P[3][2][128];      // k-half partial sums
        {
            const int e = tid >> 1, half = tid & 1;
            const f32x4* er4 = (const f32x4*)(emb + (size_t)e * 124);
            #pragma unroll
            for (int i = 0; i < 16; ++i) {
                const int idx = half * 16 + i;
                if (idx < 31) {
                    const f32x4 v = er4[idx];
                    const int k0 = idx * 4;
                    M[(k0 + 0) * PAD + e] = v.x;
                    M[(k0 + 1) * PAD + e] = v.y;
                    M[(k0 + 2) * PAD + e] = v.z;
                    M[(k0 + 3) * PAD + e] = v.w;
                }
            }
        }
        __syncthreads();

        const int e = tid & 127;
        const int h = tid >> 7;          // k-half
        const int j = blk;               // channel
        const int k0 = h * 62;

        const float* __restrict__ wzr = Wc + (size_t)j * 128;
        const float* __restrict__ wfr = Wc + (size_t)(j + 256) * 128;
        const float* __restrict__ wor = Wc + (size_t)(j + 512) * 128;

        float az = 0.f, af = 0.f, ao = 0.f;
        #pragma unroll 31
        for (int i = 0; i < 62; ++i) {
            const int k = k0 + i;
            const float mv = M[k * PAD + e];
            az = fmaf(wzr[k], mv, az);
            af = fmaf(wfr[k], mv, af);
            ao = fmaf(wor[k], mv, ao);
        }
        P[0][h][e] = az; P[1][h][e] = af; P[2][h][e] = ao;
        __syncthreads();

        if (h == 0) {
            float sz = P[0][0][e] + P[0][1][e] + bc[j];
            float sf = P[1][0][e] + P[1][1][e] + bc[j + 256];
            float so = P[2][0][e] + P[2][1][e] + bc[j + 512];
            #pragma unroll
            for (int m = 0; m < 4; ++m) {
                const float bm = bn[m];
                sz = fmaf(wzr[124 + m], bm, sz);
                sf = fmaf(wfr[124 + m], bm, sf);
                so = fmaf(wor[124 + m], bm, so);
            }
            G2h[(size_t)e * NH + j] = (f16x2){(_Float16)(sz * (-2.0f * LOG2E)),
                                              (_Float16)(sf * (-LOG2E))};
            Go[(size_t)e * NH + j] = so * (-LOG2E);
        }
    } else if (blk == 256) {
        const int j = tid;
        #pragma unroll
        for (int m = 0; m < 4; ++m) {
            const float wz = Wc[(size_t)j * 128 + 124 + m];
            const float wf = Wc[(size_t)(j + 256) * 128 + 124 + m];
            const float wo = Wc[(size_t)(j + 512) * 128 + 124 + m];
            Wg4[m * NH + j]  = (f32x2){wz * (-2.0f * LOG2E), wf * (-LOG2E)};
            Wgo4[m * NH + j] = wo * (-LOG2E);
        }
        if (tid < 64) cnt[tid] = 0;   // fresh tickets every launch
    } else {
        // rank-4 record extraction: 128 blocks x 1024 records
        const f32x4* X4 = (const f32x4*)X;
        f32x4* Xp4 = (f32x4*)Xp;
        float wn[4][7];
        #pragma unroll
        for (int m = 0; m < 4; ++m)
            #pragma unroll
            for (int n = 0; n < 7; ++n) wn[m][n] = Wn[m * 7 + n];

        const int base = (blk - 257) * 1024 + tid;
        #pragma unroll
        for (int u = 0; u < 4; ++u) {
            const int idx = base + u * 256;
            const f32x4 xa = X4[(size_t)idx * 2];
            const f32x4 xb = X4[(size_t)idx * 2 + 1];
            const int eo = ((int)xa.x) << 10;   // byte offset of 1KB G2h row
            const float xs[7] = {xa.y, xa.z, xa.w, xb.x, xb.y, xb.z, xb.w};
            float y[4];
            #pragma unroll
            for (int m = 0; m < 4; ++m) {
                float s = 0.0f;
                #pragma unroll
                for (int n = 0; n < 7; ++n) s = fmaf(wn[m][n], xs[n], s);
                y[m] = s;
            }
            Xp4[(size_t)idx * 2]     = (f32x4){__int_as_float(eo), y[0], y[1], y[2]};
            Xp4[(size_t)idx * 2 + 1] = (f32x4){y[3], 0.f, 0.f, 0.f};
        }
    }
}

__global__ __launch_bounds__(256) void scan_kernel(
    const float* __restrict__ Xp,    // [B*S][8] rank-4 records
    const f16x2* __restrict__ G2h,   // [128][256] fp16 (z',f')
    const float* __restrict__ Go,    // [128][256]
    const f32x2* __restrict__ Wg4,   // [4][256]
    const float* __restrict__ Wgo4,  // [4][256]
    float* __restrict__ AB,          // [CHUNKS][B][2][256]
    float* __restrict__ Olast,       // [B][256]
    const float* __restrict__ Wout,  // [1][256]
    const float* __restrict__ bout,  // [1]
    int* __restrict__ cnt,           // [64] tickets
    float* __restrict__ out)         // [B][1]
{
    const int b = blockIdx.x;
    const int c = blockIdx.y;
    const int j = threadIdx.x;

    const f32x4* __restrict__ xq =
        (const f32x4*)(Xp + ((size_t)b * NS + (size_t)c * STEPS) * 8);  // uniform
    const char* __restrict__ gb = (const char*)G2h;
    const int j4 = j * 4;

    const f32x2 w0 = Wg4[0 * NH + j];
    const f32x2 w1 = Wg4[1 * NH + j];
    const f32x2 w2 = Wg4[2 * NH + j];
    const f32x2 w3 = Wg4[3 * NH + j];

    float A = 1.0f, Bv = 0.0f;
    #pragma unroll
    for (int t = 0; t < STEPS; ++t) {
        const f32x4 ra = xq[2 * t];          // {eo bits, y0, y1, y2}  (s_load)
        const float y3 = xq[2 * t + 1].x;    // (s_load)
        const f16x2 gh = *(const f16x2*)(gb + (size_t)(unsigned)__float_as_int(ra.x) + j4);
        f32x2 g = (f32x2){(float)gh.x, (float)gh.y};
        g = __builtin_elementwise_fma(w0, (f32x2){ra.y, ra.y}, g);
        g = __builtin_elementwise_fma(w1, (f32x2){ra.z, ra.z}, g);
        g = __builtin_elementwise_fma(w2, (f32x2){ra.w, ra.w}, g);
        g = __builtin_elementwise_fma(w3, (f32x2){y3, y3}, g);

        const float ez = __builtin_amdgcn_exp2f(g.x);   // exp(-2 gz)
        const float ef = __builtin_amdgcn_exp2f(g.y);   // exp(-gf)
        const float az = 1.0f + ez, af = 1.0f + ef;
        const float r = __builtin_amdgcn_rcpf(az * af); // shared rcp
        const float f = r * az;                         // sigmoid(gf)
        const float z = fmaf(2.0f, r * af, -1.0f);      // tanh(gz)

        A *= f;
        Bv = fmaf(f, Bv - z, z);   // z + f*(Bv - z)
    }

    AB[(((size_t)c * NB + b) * 2 + 0) * NH + j] = A;
    AB[(((size_t)c * NB + b) * 2 + 1) * NH + j] = Bv;

    if (c == CHUNKS - 1) {
        const f32x4 la = xq[2 * (STEPS - 1)];
        const float ly3 = xq[2 * (STEPS - 1) + 1].x;
        const int eo = __float_as_int(la.x);     // e<<10 == byte offset of 1KB Go row
        float go = *(const float*)((const char*)Go + (size_t)(unsigned)eo + j * 4);
        go = fmaf(Wgo4[0 * NH + j], la.y, go);
        go = fmaf(Wgo4[1 * NH + j], la.z, go);
        go = fmaf(Wgo4[2 * NH + j], la.w, go);
        go = fmaf(Wgo4[3 * NH + j], ly3, go);
        Olast[b * NH + j] = __builtin_amdgcn_rcpf(1.0f + __builtin_amdgcn_exp2f(go));
    }

    // ---- fused combine: last chunk-block of batch b folds the 32 affines ----
    __shared__ int s_t;
    __shared__ float red[4];
    __threadfence();                     // release this block's AB/Ol writes
    __syncthreads();                     // all threads fenced
    if (j == 0) s_t = atomicAdd(&cnt[b], 1);
    __syncthreads();                     // broadcast ticket (block-uniform branch)
    if (s_t == CHUNKS - 1) {
        __threadfence();                 // acquire other blocks' writes
        float h = 0.0f;
        #pragma unroll 8
        for (int cc = 0; cc < CHUNKS; ++cc) {
            const float Av = AB[(((size_t)cc * NB + b) * 2 + 0) * NH + j];
            const float Bc = AB[(((size_t)cc * NB + b) * 2 + 1) * NH + j];
            h = fmaf(Av, h, Bc);
        }
        float v = Olast[b * NH + j] * h * Wout[j];
        #pragma unroll
        for (int off = 32; off > 0; off >>= 1) v += __shfl_down(v, off);
        if ((j & 63) == 0) red[j >> 6] = v;
        __syncthreads();
        if (j == 0) out[b] = red[0] + red[1] + red[2] + red[3] + bout[0];
    }
}

extern "C" void kernel_launch(void* const* d_in, const int* in_sizes, int n_in,
                              void* d_out, int out_size, void* d_ws, size_t ws_size,
                              hipStream_t stream) {
    const float* X    = (const float*)d_in[0];
    const float* emb  = (const float*)d_in[1];
    const float* Wn   = (const float*)d_in[2];
    const float* bn   = (const float*)d_in[3];
    const float* Wc   = (const float*)d_in[4];
    const float* bc   = (const float*)d_in[5];
    const float* Wout = (const float*)d_in[6];
    const float* bout = (const float*)d_in[7];
    float* out = (float*)d_out;

    char* w = (char*)d_ws;
    f16x2* G2h  = (f16x2*)w;                 w += 128 * NH * sizeof(f16x2);   // 128 KB
    float* Go   = (float*)w;                 w += 128 * NH * sizeof(float);   // 128 KB
    f32x2* Wg4  = (f32x2*)w;                 w += 4 * NH * sizeof(f32x2);
    float* Wgo4 = (float*)w;                 w += 4 * NH * sizeof(float);
    float* AB   = (float*)w;                 w += (size_t)CHUNKS * NB * 2 * NH * sizeof(float); // 4 MB
    float* Ol   = (float*)w;                 w += NB * NH * sizeof(float);
    float* Xp   = (float*)w;                 w += (size_t)NB * NS * 8 * sizeof(float);          // 4 MB
    int*   cnt  = (int*)w;

    precompute_kernel<<<385, 256, 0, stream>>>(X, emb, Wn, bn, Wc, bc,
                                               G2h, Go, Wg4, Wgo4, Xp, cnt);
    dim3 grid(NB, CHUNKS);
    scan_kernel<<<grid, 256, 0, stream>>>(Xp, G2h, Go, Wg4, Wgo4, AB, Ol,
                                          Wout, bout, cnt, out);
}

// Round 10
// 39.722 us; speedup vs baseline: 4.7807x; 4.7807x over previous
//
#include <hip/hip_runtime.h>

// QRNN fused kernel for MI355X.
// B=64, S=2048, VOCAB=128, HIDDEN=256, gates=768, emb=124, num=7.
//
//  - precompute_kernel (one grid, three roles):
//      blocks 0..255  : GEMM, one channel j per block. Writes fp16-packed exp2-domain
//                       table G2h[e][j]={z',f'} (1KB rows) + f32 Go[e][j]=o'.
//      block  256     : rank-4 numeric weights Wg4/Wgo4.
//      blocks 257..384: rank-4 records Xp[b*S+t]={eo=e<<10 bits, y0..y2}{y3,pad}.
//  - scan_kernel: affine recurrence h = f*h + (1-f)*z, chunked scan (32 x 64 steps).
//      THE TABLE LIVES IN LDS: grid (256,2), 1024 thr = 8 (b,c)-slices x 128 channels;
//      each block stages its 64KB j-half of G2h once, then the per-step table access
//      is a conflict-free ds_read_b32 (lane stride 4B -> 2-way, free). This removes
//      the per-CU L1-miss storm (table >> 32KB L1) that pinned the scan at ~29us
//      across every schedule variant (r4-r8). 64KB LDS -> 2 blocks/CU -> 8 waves/SIMD.
//      Full 64-step unroll, s_load records, shared-rcp activation.
//      NO device-scope fences/atomics: r9 proved __threadfence() per block costs an
//      L2 writeback on multi-XCD CDNA (186us!). Kernel boundary instead.
//  - combine_kernel: fold 32 chunk affines, apply o (last step), dot W_out.

typedef float    f32x2 __attribute__((ext_vector_type(2)));
typedef float    f32x4 __attribute__((ext_vector_type(4)));
typedef _Float16 f16x2 __attribute__((ext_vector_type(2)));

#define NB 64
#define NS 2048
#define NH 256
#define CHUNKS 32
#define STEPS (NS / CHUNKS)   // 64
#define LOG2E 1.4426950408889634f
#define PAD 129
#define JH 128                // channels per j-half

__global__ __launch_bounds__(256) void precompute_kernel(
    const float* __restrict__ X,     // [B][S][8]
    const float* __restrict__ emb,   // [128][124]
    const float* __restrict__ Wn,    // [4][7]
    const float* __restrict__ bn,    // [4]
    const float* __restrict__ Wc,    // [768][128]
    const float* __restrict__ bc,    // [768]
    f16x2* __restrict__ G2h,         // out [128e][256j]  (z', f') fp16, exp2-domain
    float* __restrict__ Go,          // out [128e][256j]  o' (f32)
    f32x2* __restrict__ Wg4,         // out [4][256]
    float* __restrict__ Wgo4,        // out [4][256]
    float* __restrict__ Xp)          // out [B*S][8] packed rank-4 records
{
    const int tid = threadIdx.x;
    const int blk = blockIdx.x;

    if (blk < 256) {
        __shared__ float M[124 * PAD];      // emb^T: M[k*PAD + e] = emb[e][k]
        __shared__ float P[3][2][128];      // k-half partial sums
        {
            const int e = tid >> 1, half = tid & 1;
            const f32x4* er4 = (const f32x4*)(emb + (size_t)e * 124);
            #pragma unroll
            for (int i = 0; i < 16; ++i) {
                const int idx = half * 16 + i;
                if (idx < 31) {
                    const f32x4 v = er4[idx];
                    const int k0 = idx * 4;
                    M[(k0 + 0) * PAD + e] = v.x;
                    M[(k0 + 1) * PAD + e] = v.y;
                    M[(k0 + 2) * PAD + e] = v.z;
                    M[(k0 + 3) * PAD + e] = v.w;
                }
            }
        }
        __syncthreads();

        const int e = tid & 127;
        const int h = tid >> 7;          // k-half
        const int j = blk;               // channel
        const int k0 = h * 62;

        const float* __restrict__ wzr = Wc + (size_t)j * 128;
        const float* __restrict__ wfr = Wc + (size_t)(j + 256) * 128;
        const float* __restrict__ wor = Wc + (size_t)(j + 512) * 128;

        float az = 0.f, af = 0.f, ao = 0.f;
        #pragma unroll 31
        for (int i = 0; i < 62; ++i) {
            const int k = k0 + i;
            const float mv = M[k * PAD + e];
            az = fmaf(wzr[k], mv, az);
            af = fmaf(wfr[k], mv, af);
            ao = fmaf(wor[k], mv, ao);
        }
        P[0][h][e] = az; P[1][h][e] = af; P[2][h][e] = ao;
        __syncthreads();

        if (h == 0) {
            float sz = P[0][0][e] + P[0][1][e] + bc[j];
            float sf = P[1][0][e] + P[1][1][e] + bc[j + 256];
            float so = P[2][0][e] + P[2][1][e] + bc[j + 512];
            #pragma unroll
            for (int m = 0; m < 4; ++m) {
                const float bm = bn[m];
                sz = fmaf(wzr[124 + m], bm, sz);
                sf = fmaf(wfr[124 + m], bm, sf);
                so = fmaf(wor[124 + m], bm, so);
            }
            G2h[(size_t)e * NH + j] = (f16x2){(_Float16)(sz * (-2.0f * LOG2E)),
                                              (_Float16)(sf * (-LOG2E))};
            Go[(size_t)e * NH + j] = so * (-LOG2E);
        }
    } else if (blk == 256) {
        const int j = tid;
        #pragma unroll
        for (int m = 0; m < 4; ++m) {
            const float wz = Wc[(size_t)j * 128 + 124 + m];
            const float wf = Wc[(size_t)(j + 256) * 128 + 124 + m];
            const float wo = Wc[(size_t)(j + 512) * 128 + 124 + m];
            Wg4[m * NH + j]  = (f32x2){wz * (-2.0f * LOG2E), wf * (-LOG2E)};
            Wgo4[m * NH + j] = wo * (-LOG2E);
        }
    } else {
        // rank-4 record extraction: 128 blocks x 1024 records
        const f32x4* X4 = (const f32x4*)X;
        f32x4* Xp4 = (f32x4*)Xp;
        float wn[4][7];
        #pragma unroll
        for (int m = 0; m < 4; ++m)
            #pragma unroll
            for (int n = 0; n < 7; ++n) wn[m][n] = Wn[m * 7 + n];

        const int base = (blk - 257) * 1024 + tid;
        #pragma unroll
        for (int u = 0; u < 4; ++u) {
            const int idx = base + u * 256;
            const f32x4 xa = X4[(size_t)idx * 2];
            const f32x4 xb = X4[(size_t)idx * 2 + 1];
            const int eo = ((int)xa.x) << 10;   // byte offset of 1KB G2h/Go row
            const float xs[7] = {xa.y, xa.z, xa.w, xb.x, xb.y, xb.z, xb.w};
            float y[4];
            #pragma unroll
            for (int m = 0; m < 4; ++m) {
                float s = 0.0f;
                #pragma unroll
                for (int n = 0; n < 7; ++n) s = fmaf(wn[m][n], xs[n], s);
                y[m] = s;
            }
            Xp4[(size_t)idx * 2]     = (f32x4){__int_as_float(eo), y[0], y[1], y[2]};
            Xp4[(size_t)idx * 2 + 1] = (f32x4){y[3], 0.f, 0.f, 0.f};
        }
    }
}

__global__ __launch_bounds__(1024) void scan_kernel(
    const float* __restrict__ Xp,    // [B*S][8] rank-4 records
    const f16x2* __restrict__ G2h,   // [128][256] fp16 (z',f')
    const float* __restrict__ Go,    // [128][256]
    const f32x2* __restrict__ Wg4,   // [4][256]
    const float* __restrict__ Wgo4,  // [4][256]
    float* __restrict__ AB,          // [CHUNKS][B][2][256]
    float* __restrict__ Olast)       // [B][256]
{
    __shared__ f16x2 T[128 * JH];    // 64 KB: this block's j-half of the table

    const int tid = threadIdx.x;
    const int jbase = blockIdx.y * JH;

    // ---- stage j-half of G2h: 4096 uint4, coalesced, 4 iters
    {
        const uint4* __restrict__ src = (const uint4*)G2h;   // row e = 64 uint4
        uint4* dst = (uint4*)T;
        const int colbase = jbase >> 2;                       // 32 uint4 per half-row
        #pragma unroll
        for (int i = tid; i < 4096; i += 1024) {
            const int e = i >> 5, c16 = i & 31;
            dst[i] = src[e * 64 + colbase + c16];
        }
    }
    __syncthreads();

    const int slice = tid >> 7;          // 0..7
    const int jj = tid & (JH - 1);       // 0..127
    const int widx = __builtin_amdgcn_readfirstlane((int)blockIdx.x * 8 + slice);
    const int b = widx >> 5;
    const int c = widx & (CHUNKS - 1);
    const int j = jbase + jj;

    const f32x4* __restrict__ xq =
        (const f32x4*)(Xp + ((size_t)b * NS + (size_t)c * STEPS) * 8);  // wave-uniform

    const f32x2 w0 = Wg4[0 * NH + j];
    const f32x2 w1 = Wg4[1 * NH + j];
    const f32x2 w2 = Wg4[2 * NH + j];
    const f32x2 w3 = Wg4[3 * NH + j];

    float A = 1.0f, Bv = 0.0f;
    #pragma unroll
    for (int t = 0; t < STEPS; ++t) {
        const f32x4 ra = xq[2 * t];          // {eo bits, y0, y1, y2}  (s_load)
        const float y3 = xq[2 * t + 1].x;    // (s_load)
        const unsigned eo = (unsigned)__float_as_int(ra.x);   // e<<10
        const f16x2 gh = T[(eo >> 3) + jj];  // LDS: e*128 + jj, conflict-free
        f32x2 g = (f32x2){(float)gh.x, (float)gh.y};
        g = __builtin_elementwise_fma(w0, (f32x2){ra.y, ra.y}, g);
        g = __builtin_elementwise_fma(w1, (f32x2){ra.z, ra.z}, g);
        g = __builtin_elementwise_fma(w2, (f32x2){ra.w, ra.w}, g);
        g = __builtin_elementwise_fma(w3, (f32x2){y3, y3}, g);

        const float ez = __builtin_amdgcn_exp2f(g.x);   // exp(-2 gz)
        const float ef = __builtin_amdgcn_exp2f(g.y);   // exp(-gf)
        const float az = 1.0f + ez, af = 1.0f + ef;
        const float r = __builtin_amdgcn_rcpf(az * af); // shared rcp
        const float f = r * az;                         // sigmoid(gf)
        const float z = fmaf(2.0f, r * af, -1.0f);      // tanh(gz)

        A *= f;
        Bv = fmaf(f, Bv - z, z);   // z + f*(Bv - z)
    }

    AB[(((size_t)c * NB + b) * 2 + 0) * NH + j] = A;
    AB[(((size_t)c * NB + b) * 2 + 1) * NH + j] = Bv;

    if (c == CHUNKS - 1) {
        const f32x4 la = xq[2 * (STEPS - 1)];
        const float ly3 = xq[2 * (STEPS - 1) + 1].x;
        const unsigned eo = (unsigned)__float_as_int(la.x);   // 1KB Go row offset
        float go = *(const float*)((const char*)Go + eo + (size_t)j * 4);
        go = fmaf(Wgo4[0 * NH + j], la.y, go);
        go = fmaf(Wgo4[1 * NH + j], la.z, go);
        go = fmaf(Wgo4[2 * NH + j], la.w, go);
        go = fmaf(Wgo4[3 * NH + j], ly3, go);
        Olast[b * NH + j] = __builtin_amdgcn_rcpf(1.0f + __builtin_amdgcn_exp2f(go));
    }
}

__global__ __launch_bounds__(256) void combine_kernel(
    const float* __restrict__ AB,     // [CHUNKS][B][2][256]
    const float* __restrict__ Olast,  // [B][256]
    const float* __restrict__ Wout,   // [1][256]
    const float* __restrict__ bout,   // [1]
    float* __restrict__ out)          // [B][1]
{
    const int b = blockIdx.x;
    const int j = threadIdx.x;

    float h = 0.0f;
    #pragma unroll 8
    for (int c = 0; c < CHUNKS; ++c) {
        const float A  = AB[(((size_t)c * NB + b) * 2 + 0) * NH + j];
        const float Bv = AB[(((size_t)c * NB + b) * 2 + 1) * NH + j];
        h = fmaf(A, h, Bv);
    }
    float v = Olast[b * NH + j] * h * Wout[j];

    #pragma unroll
    for (int off = 32; off > 0; off >>= 1) v += __shfl_down(v, off);
    __shared__ float red[4];
    if ((j & 63) == 0) red[j >> 6] = v;
    __syncthreads();
    if (j == 0) out[b] = red[0] + red[1] + red[2] + red[3] + bout[0];
}

extern "C" void kernel_launch(void* const* d_in, const int* in_sizes, int n_in,
                              void* d_out, int out_size, void* d_ws, size_t ws_size,
                              hipStream_t stream) {
    const float* X    = (const float*)d_in[0];
    const float* emb  = (const float*)d_in[1];
    const float* Wn   = (const float*)d_in[2];
    const float* bn   = (const float*)d_in[3];
    const float* Wc   = (const float*)d_in[4];
    const float* bc   = (const float*)d_in[5];
    const float* Wout = (const float*)d_in[6];
    const float* bout = (const float*)d_in[7];
    float* out = (float*)d_out;

    char* w = (char*)d_ws;
    f16x2* G2h  = (f16x2*)w;   w += 128 * NH * sizeof(f16x2);   // 128 KB
    float* Go   = (float*)w;   w += 128 * NH * sizeof(float);   // 128 KB
    f32x2* Wg4  = (f32x2*)w;   w += 4 * NH * sizeof(f32x2);
    float* Wgo4 = (float*)w;   w += 4 * NH * sizeof(float);
    float* AB   = (float*)w;   w += (size_t)CHUNKS * NB * 2 * NH * sizeof(float); // 4 MB
    float* Ol   = (float*)w;   w += NB * NH * sizeof(float);
    float* Xp   = (float*)w;   w += (size_t)NB * NS * 8 * sizeof(float);          // 4 MB

    precompute_kernel<<<385, 256, 0, stream>>>(X, emb, Wn, bn, Wc, bc,
                                               G2h, Go, Wg4, Wgo4, Xp);
    dim3 gridS(256, 2);
    scan_kernel<<<gridS, 1024, 0, stream>>>(Xp, G2h, Go, Wg4, Wgo4, AB, Ol);
    combine_kernel<<<NB, 256, 0, stream>>>(AB, Ol, Wout, bout, out);
}